// Round 1
// baseline (271.183 us; speedup 1.0000x reference)
//
#include <hip/hip_runtime.h>
#include <math.h>

// FastFood upsample: out = fwht_2^20( (fwht-replicated y)[Pi]*GG )[:TOTAL]/scale
// y[b] = fwht_1024(z[b] * BB[:1024]); m1[j] = y[j & 1023] (input sparse).
// H_{2^20} = H_{2^10} (x) H_{2^10}:
//   pass1: U[b][kh][jl] = FWHT_1024 over kl of t[b][kh][kl], t = y[Pi&1023]*GG
//   pass2: out[b][jh][jl] = FWHT_1024 over kh of U[b][kh][jl], scaled+remapped

#define TS 33            // LDS tile stride (pad 32->33: conflict-free)
#define TOTAL_DIM 984064
#define OUT_B0 786432    // 768*1024
#define OUT_B1 787200    // + 768
#define OUT_B2 983808    // + 192*1024
#define OFF1 25165824L   // 32*786432
#define OFF2 25190400L   // + 32*768
#define OFF3 31481856L   // + 32*196608

// Radix-4 FWHT over leading index (1024) of tile[1024][TS], 32 columns live.
// 1024 threads. Covers stages h=1..512 as 5 radix-4 passes.
__device__ __forceinline__ void fwht1024_cols(float* tile, int tid) {
    const int col = tid & 31;
    const int mbase = tid >> 5;
    #pragma unroll
    for (int h = 1; h < 1024; h *= 4) {
        __syncthreads();
        const int d = h * TS;
        #pragma unroll
        for (int s = 0; s < 8; ++s) {
            const int m = mbase + (s << 5);          // quad index 0..255
            const int lo = m & (h - 1);
            const int i0 = ((m - lo) << 2) + lo;     // insert 2 zero bits at h
            const int p0 = i0 * TS + col;
            float a = tile[p0];
            float b = tile[p0 + d];
            float c = tile[p0 + 2 * d];
            float e = tile[p0 + 3 * d];
            float apb = a + b, amb = a - b, cpe = c + e, cme = c - e;
            tile[p0]         = apb + cpe;
            tile[p0 + d]     = amb + cme;
            tile[p0 + 2 * d] = apb - cpe;
            tile[p0 + 3 * d] = amb - cme;
        }
    }
    __syncthreads();
}

// Pass 0: y_t[i*32+b] = fwht_1024(z[b]*BB[:1024])[i]   (32x1024, one WG)
__global__ __launch_bounds__(1024) void k_y(const float* __restrict__ z,
                                            const float* __restrict__ BBv,
                                            float* __restrict__ y_t) {
    __shared__ float tile[1024 * TS];
    const int tid = threadIdx.x;
    #pragma unroll 4
    for (int s = 0; s < 32; ++s) {                   // b = s, i = tid
        tile[tid * TS + s] = z[s * 1024 + tid] * BBv[tid];
    }
    fwht1024_cols(tile, tid);
    const int b = tid & 31;
    #pragma unroll 4
    for (int s = 0; s < 32; ++s) {
        const int i = (tid >> 5) + (s << 5);
        y_t[i * 32 + b] = tile[i * TS + b];
    }
}

// Pass 1: one block per kh; all 32 batch rows share Pi/GG row.
__global__ __launch_bounds__(1024) void k_pass1(const float* __restrict__ y_t,
                                                const float* __restrict__ GG,
                                                const int* __restrict__ Pi,
                                                float* __restrict__ U) {
    __shared__ float tile[1024 * TS];
    __shared__ int   p_s[1024];
    __shared__ float g_s[1024];
    const int tid = threadIdx.x;
    const int kh = blockIdx.x;
    const long base = (long)kh << 10;
    p_s[tid] = Pi[base + tid] & 1023;
    g_s[tid] = GG[base + tid];
    __syncthreads();

    const int b = tid & 31;
    const int klbase = tid >> 5;
    #pragma unroll 4
    for (int s = 0; s < 32; ++s) {
        const int kl = klbase + (s << 5);
        tile[kl * TS + b] = y_t[p_s[kl] * 32 + b] * g_s[kl];
    }
    fwht1024_cols(tile, tid);
    const int b2 = tid >> 5;
    const int jlb = tid & 31;
    const long wbase = ((long)b2 * 1024 + kh) * 1024;
    #pragma unroll 4
    for (int s = 0; s < 32; ++s) {
        const int jl = jlb + (s << 5);
        U[wbase + jl] = tile[jl * TS + b2];
    }
}

// Pass 2: one block per (jl-tile, b): FWHT over kh, scale, remap to concat layout.
__global__ __launch_bounds__(1024) void k_pass2(const float* __restrict__ U,
                                                const float* __restrict__ divisor,
                                                float* __restrict__ out) {
    __shared__ float tile[1024 * TS];
    const int tid = threadIdx.x;
    const int jl0 = blockIdx.x << 5;   // 0..992 step 32
    const int b   = blockIdx.y;        // 0..31
    const int jl = tid & 31;
    const int khbase = tid >> 5;
    const float* Ub = U + ((long)b << 20);
    #pragma unroll 4
    for (int s = 0; s < 32; ++s) {
        const int kh = khbase + (s << 5);
        tile[kh * TS + jl] = Ub[((long)kh << 10) + jl0 + jl];
    }
    fwht1024_cols(tile, tid);
    const float inv = 1.0f / (divisor[0] * sqrtf((float)TOTAL_DIM / 1048576.0f));
    const int jhbase = tid >> 5;
    #pragma unroll 2
    for (int s = 0; s < 31; ++s) {
        const int jh = jhbase + (s << 5);
        if (jh > 960) continue;                       // TOTAL_DIM = 961*1024
        const int j = (jh << 10) + jl0 + jl;
        long oidx;
        if (j < OUT_B0)      oidx = (long)b * 786432 + j;
        else if (j < OUT_B1) oidx = OFF1 + (long)b * 768 + (j - OUT_B0);
        else if (j < OUT_B2) oidx = OFF2 + (long)b * 196608 + (j - OUT_B1);
        else                 oidx = OFF3 + (long)b * 256 + (j - OUT_B2);
        out[oidx] = tile[jh * TS + jl] * inv;
    }
}

extern "C" void kernel_launch(void* const* d_in, const int* in_sizes, int n_in,
                              void* d_out, int out_size, void* d_ws, size_t ws_size,
                              hipStream_t stream) {
    const float* z   = (const float*)d_in[0];   // [32,1024]
    const float* BBv = (const float*)d_in[1];   // [2^20]
    const float* GG  = (const float*)d_in[2];   // [2^20]
    const float* dv  = (const float*)d_in[3];   // [1]
    const int*   Pi  = (const int*)d_in[4];     // [2^20]
    float* out = (float*)d_out;

    float* y_t = (float*)d_ws;                              // 32*1024 f32 = 128 KB
    float* U   = (float*)((char*)d_ws + (size_t)131072);    // 32*2^20 f32 = 128 MB

    k_y<<<1, 1024, 0, stream>>>(z, BBv, y_t);
    k_pass1<<<1024, 1024, 0, stream>>>(y_t, GG, Pi, U);
    k_pass2<<<dim3(32, 32), 1024, 0, stream>>>(U, dv, out);
}

// Round 2
// 246.509 us; speedup vs baseline: 1.1001x; 1.1001x over previous
//
#include <hip/hip_runtime.h>
#include <math.h>

// FastFood upsample, register-resident FWHT version.
// y[b] = fwht_1024(z[b] * BB[:1024]);  m1[j] = y[j & 1023]  (input sparse).
// H_{2^20} = H_{2^10} (x) H_{2^10}:
//   pass1: U[b][kh][jl] = FWHT_1024 over kl of t[b][kh][kl], t = y[Pi&1023]*GG
//   pass2: out[b][jh][jl] = FWHT_1024 over kh of U[b][kh][jl], scaled+remapped
// Each FWHT-1024 instance lives in ONE wave: i = r*64 + lane, 16 f32 regs.
// bits 0-1: DPP quad_perm; bits 2-4: ds_swizzle xor; bit 5: shfl_xor(32);
// bits 6-9: in-register add/sub. LDS only for coalesced staging/transpose.

#define TS 17            // LDS tile word-stride for 16 columns (+1 pad)
#define TOTAL_DIM 984064
#define OUT_B0 786432    // 768*1024
#define OUT_B1 787200    // + 768
#define OUT_B2 983808    // + 192*1024
#define OFF1 25165824L   // 32*786432
#define OFF2 25190400L   // + 32*768
#define OFF3 31481856L   // + 32*196608

template<int CTRL>
__device__ __forceinline__ float pdpp(float x) {
    return __int_as_float(__builtin_amdgcn_update_dpp(
        0, __float_as_int(x), CTRL, 0xF, 0xF, true));
}
template<int OFS>
__device__ __forceinline__ float pswz(float x) {
    return __int_as_float(__builtin_amdgcn_ds_swizzle(__float_as_int(x), OFS));
}

// Full unnormalized FWHT-1024 over i = r*64 + lane, in registers.
__device__ __forceinline__ void fwht_wave(float v[16], int lane) {
    const float s1  = (lane & 1)  ? -1.f : 1.f;
    const float s2  = (lane & 2)  ? -1.f : 1.f;
    const float s4  = (lane & 4)  ? -1.f : 1.f;
    const float s8  = (lane & 8)  ? -1.f : 1.f;
    const float s16 = (lane & 16) ? -1.f : 1.f;
    const float s32 = (lane & 32) ? -1.f : 1.f;
    #pragma unroll
    for (int r = 0; r < 16; ++r) { float p = pdpp<0xB1>(v[r]);   v[r] = fmaf(s1,  v[r], p); }
    #pragma unroll
    for (int r = 0; r < 16; ++r) { float p = pdpp<0x4E>(v[r]);   v[r] = fmaf(s2,  v[r], p); }
    #pragma unroll
    for (int r = 0; r < 16; ++r) { float p = pswz<0x101F>(v[r]); v[r] = fmaf(s4,  v[r], p); }
    #pragma unroll
    for (int r = 0; r < 16; ++r) { float p = pswz<0x201F>(v[r]); v[r] = fmaf(s8,  v[r], p); }
    #pragma unroll
    for (int r = 0; r < 16; ++r) { float p = pswz<0x401F>(v[r]); v[r] = fmaf(s16, v[r], p); }
    #pragma unroll
    for (int r = 0; r < 16; ++r) { float p = __shfl_xor(v[r], 32, 64); v[r] = fmaf(s32, v[r], p); }
    #pragma unroll
    for (int m = 1; m <= 8; m <<= 1) {
        #pragma unroll
        for (int r = 0; r < 16; ++r) {
            if (!(r & m)) {
                float a = v[r], b = v[r | m];
                v[r] = a + b;
                v[r | m] = a - b;
            }
        }
    }
}

// Pass 0: y_t[i*32+b] = fwht_1024(z[b]*BB[:1024])[i].  2 blocks x 16 waves.
__global__ __launch_bounds__(1024) void k_y(const float* __restrict__ z,
                                            const float* __restrict__ BBv,
                                            float* __restrict__ y_t) {
    __shared__ float tile[1024 * TS];
    const int tid = threadIdx.x;
    const int lane = tid & 63, w = tid >> 6;
    const int b = (blockIdx.x << 4) + w;
    float v[16];
    #pragma unroll
    for (int r = 0; r < 16; ++r) {
        const int i = r * 64 + lane;
        v[r] = z[(b << 10) + i] * BBv[i];
    }
    fwht_wave(v, lane);
    #pragma unroll
    for (int r = 0; r < 16; ++r) tile[(r * 64 + lane) * TS + w] = v[r];
    __syncthreads();
    const int bcol = tid & 15, i0 = tid >> 4;
    #pragma unroll 4
    for (int s = 0; s < 16; ++s) {
        const int i = i0 + (s << 6);
        y_t[(i << 5) + (blockIdx.x << 4) + bcol] = tile[i * TS + bcol];
    }
}

// Pass 1: block = (kh, bgroup of 16 b). Stage t coalesced -> per-wave column
// -> reg FWHT -> coalesced U write.
__global__ __launch_bounds__(1024, 8) void k_pass1(const float* __restrict__ y_t,
                                                   const float* __restrict__ GG,
                                                   const int* __restrict__ Pi,
                                                   float* __restrict__ U) {
    __shared__ float tile[1024 * TS];
    __shared__ float g_s[1024];
    __shared__ int   p_s[1024];
    const int tid = threadIdx.x;
    const int kh = blockIdx.x, bg = blockIdx.y;
    p_s[tid] = Pi[(kh << 10) + tid] & 1023;
    g_s[tid] = GG[(kh << 10) + tid];
    __syncthreads();
    const int b = tid & 15, kl0 = tid >> 4;
    #pragma unroll 4
    for (int s = 0; s < 16; ++s) {
        const int kl = kl0 + (s << 6);
        tile[kl * TS + b] = y_t[(p_s[kl] << 5) + (bg << 4) + b] * g_s[kl];
    }
    __syncthreads();
    const int lane = tid & 63, w = tid >> 6;
    float v[16];
    #pragma unroll
    for (int r = 0; r < 16; ++r) v[r] = tile[(r * 64 + lane) * TS + w];
    fwht_wave(v, lane);
    const long ub = ((long)((bg << 4) + w) << 20) + ((long)kh << 10);
    #pragma unroll
    for (int r = 0; r < 16; ++r) U[ub + r * 64 + lane] = v[r];
}

// Pass 2: block = (jl-tile of 16, b). Stage U coalesced -> per-wave column
// -> reg FWHT over kh -> LDS transpose -> coalesced remapped out write.
__global__ __launch_bounds__(1024, 8) void k_pass2(const float* __restrict__ U,
                                                   const float* __restrict__ divisor,
                                                   float* __restrict__ out) {
    __shared__ float tile[1024 * TS];
    const int tid = threadIdx.x;
    const int jl0 = blockIdx.x << 4;   // 0..1008 step 16
    const int bb  = blockIdx.y;        // 0..31
    const float* Ub = U + ((long)bb << 20);
    const int jl = tid & 15, k0 = tid >> 4;
    #pragma unroll 4
    for (int s = 0; s < 16; ++s) {
        const int kh = k0 + (s << 6);
        tile[kh * TS + jl] = Ub[((long)kh << 10) + jl0 + jl];
    }
    __syncthreads();
    const int lane = tid & 63, w = tid >> 6;
    float v[16];
    #pragma unroll
    for (int r = 0; r < 16; ++r) v[r] = tile[(r * 64 + lane) * TS + w];
    fwht_wave(v, lane);
    const float inv = 1.0f / (divisor[0] * sqrtf((float)TOTAL_DIM / 1048576.0f));
    #pragma unroll
    for (int r = 0; r < 16; ++r) tile[(r * 64 + lane) * TS + w] = v[r] * inv;
    __syncthreads();
    #pragma unroll 2
    for (int s = 0; s < 16; ++s) {
        const int jh = k0 + (s << 6);
        if (jh <= 960) {                                  // TOTAL = 961*1024
            const int j = (jh << 10) + jl0 + jl;
            long oidx;
            if (j < OUT_B0)      oidx = (long)bb * 786432 + j;
            else if (j < OUT_B1) oidx = OFF1 + (long)bb * 768 + (j - OUT_B0);
            else if (j < OUT_B2) oidx = OFF2 + (long)bb * 196608 + (j - OUT_B1);
            else                 oidx = OFF3 + (long)bb * 256 + (j - OUT_B2);
            out[oidx] = tile[jh * TS + jl];
        }
    }
}

extern "C" void kernel_launch(void* const* d_in, const int* in_sizes, int n_in,
                              void* d_out, int out_size, void* d_ws, size_t ws_size,
                              hipStream_t stream) {
    const float* z   = (const float*)d_in[0];   // [32,1024]
    const float* BBv = (const float*)d_in[1];   // [2^20]
    const float* GG  = (const float*)d_in[2];   // [2^20]
    const float* dv  = (const float*)d_in[3];   // [1]
    const int*   Pi  = (const int*)d_in[4];     // [2^20]
    float* out = (float*)d_out;

    float* y_t = (float*)d_ws;                              // 32*1024 f32 = 128 KB
    float* U   = (float*)((char*)d_ws + (size_t)131072);    // 32*2^20 f32 = 128 MB

    k_y<<<2, 1024, 0, stream>>>(z, BBv, y_t);
    k_pass1<<<dim3(1024, 2), 1024, 0, stream>>>(y_t, GG, Pi, U);
    k_pass2<<<dim3(64, 32), 1024, 0, stream>>>(U, dv, out);
}